// Round 10
// baseline (61892.023 us; speedup 1.0000x reference)
//
#include <hip/hip_runtime.h>
#include <stdint.h>

#define Tn 100
#define Dn 51
#define Hn 128
#define BR 8        // batch rows per PAIR (both WGs of a pair share these rows)
#define NWG 512     // 256 pairs x 2 roles; pair = wg&255, role = wg>>8, partner = wg^256
#define NTH 512     // 8 waves per WG
#define RP 264      // xhA row stride in bf16 elems
#define NC 256      // own N-cols per role (half of 4H)
#define FWTE (128*52)

typedef unsigned int uint32;
typedef unsigned short u16;
typedef short s16x8 __attribute__((ext_vector_type(8)));   // 8 bf16 = 4 VGPRs
typedef float f32x4v __attribute__((ext_vector_type(4)));

__device__ __forceinline__ float rcp_(float x){ return __builtin_amdgcn_rcpf(x); }
__device__ __forceinline__ float sigm(float x){ return rcp_(1.f + __expf(-x)); }
__device__ __forceinline__ float tanh_(float x){ return 1.f - 2.f*rcp_(1.f + __expf(2.f*x)); }

__device__ __forceinline__ u16 f2bf(float f){
  uint32 u = __float_as_uint(f);
  return (u16)((u + 0x7fffu + ((u >> 16) & 1u)) >> 16);
}
__device__ __forceinline__ float bf2f(u16 u){ return __uint_as_float(((uint32)u)<<16); }

// A-fragment trick: row r = bf16-hi, row r+8 = bf16-lo; one MFMA does both pumps.
__device__ __forceinline__ void wr_xh(u16* __restrict__ xhA, int r, int k, float v){
  u16 h = f2bf(v);
  xhA[r*RP + k]     = h;
  xhA[(r+8)*RP + k] = f2bf(v - bf2f(h));
}

struct WP {
  const float* W[6];   // [4H, din]
  const float* U[6];   // [4H, H]
  const float* Bb[6];  // [4H]
  const float* fW;     // [D, H]
  const float* fb;     // [D]
};

// wsw: per (layer,role) 65536 u16 = 16 N-tiles of the role's 256 cols.
// Own-col c' = gate*64 + u (u = unit index within role); actual col
// C = gate*128 + role*64 + u. Chunk (n,s) at n*4096 + s*512 + lane*8 + j holds
// Wc[k = s*32+(lane>>4)*8+j][c' = n*16+(lane&15)], Wc=[Wih|Whh], zero-padded.
// bias: same permuted order, [l][role][c'].  fwt: [128][52] k-major f32.
// flags: NWG u32, zeroed EVERY launch by prep (re-poison safety: spin counters
// must restart; prep precedes lstm in-stream each replay).
#define PREP_TOTAL (6*131072 + 6*512 + FWTE + 64 + NWG)
__global__ void prep_kernel(WP p, u16* __restrict__ wsw, float* __restrict__ bias,
                            float* __restrict__ fwt, float* __restrict__ fbw,
                            uint32* __restrict__ flags)
{
  int gid = blockIdx.x*256 + threadIdx.x;
  if (gid >= PREP_TOTAL) return;
  if (gid < 6*131072){
    int l    = gid >> 17;
    int e    = gid & 131071;
    int role = e >> 16;
    int e2   = e & 65535;
    int n    = e2 >> 12;
    int s    = (e2 >> 9) & 7;
    int lane = (e2 >> 3) & 63;
    int j    = e2 & 7;
    int k    = s*32 + (lane >> 4)*8 + j;
    int cown = n*16 + (lane & 15);
    int C    = (cown >> 6)*128 + role*64 + (cown & 63);
    int din  = (l % 3 == 0) ? Dn : Hn;
    int K    = din + Hn;
    u16 v = 0;
    if (k < K){
      float f = (k < din) ? p.W[l][(size_t)C*din + k] : p.U[l][(size_t)C*Hn + (k - din)];
      v = f2bf(f);
    }
    wsw[gid] = v;
  } else if (gid < 6*131072 + 6*512){
    int i = gid - 6*131072;
    int l = i >> 9, c9 = i & 511;
    int role = c9 >> 8, cown = c9 & 255;
    bias[i] = p.Bb[l][(cown >> 6)*128 + role*64 + (cown & 63)];
  } else if (gid < 6*131072 + 6*512 + FWTE){
    int i = gid - (6*131072 + 6*512);
    int k = i / 52, d = i % 52;
    fwt[i] = (d < Dn) ? p.fW[(size_t)d*Hn + k] : 0.f;
  } else if (gid < 6*131072 + 6*512 + FWTE + 64){
    int d = gid - (6*131072 + 6*512 + FWTE);
    fbw[d] = (d < Dn) ? p.fb[d] : 0.f;
  } else {
    flags[gid - (6*131072 + 6*512 + FWTE + 64)] = 0u;
  }
}

// LDS-only barrier (drains DS, not vmcnt).
__device__ __forceinline__ void bar_lds(){
  asm volatile("s_waitcnt lgkmcnt(0)" ::: "memory");
  __builtin_amdgcn_s_barrier();
}

// gates[r][c'] = sum_k xh[r][k]*Wc[k][c'] (bias added in epilogue regs).
// Wave w owns own-tiles n0=2w, 2w+1. R2's proven unroll-2 loop, untouched.
// C/D: col=lane&15, row=(lane>>4)*4+reg -> rows in lanes 0-31 after fold.
template<int S>
__device__ __forceinline__ void gemm_mfma(const u16* __restrict__ wsl,
                                          float bv0, float bv1,
                                          const u16* __restrict__ xh_in,
                                          float* __restrict__ gates,
                                          int wave, int lane)
{
  const int mrow = lane & 15, kgrp = lane >> 4;
  const int n0 = wave*2;
  const u16* bp0 = wsl + n0*4096 + lane*8;
  const int aoff = mrow*RP + (kgrp << 3);
  f32x4v acc0 = {0.f,0.f,0.f,0.f}, acc1 = {0.f,0.f,0.f,0.f};
  #pragma unroll 2
  for (int s=0; s<S; s++){
    s16x8 a  = *(const s16x8*)(xh_in + aoff + s*32);
    s16x8 b0 = *(const s16x8*)(bp0 + s*512);
    s16x8 b1 = *(const s16x8*)(bp0 + 4096 + s*512);
    acc0 = __builtin_amdgcn_mfma_f32_16x16x32_bf16(a, b0, acc0, 0, 0, 0);
    acc1 = __builtin_amdgcn_mfma_f32_16x16x32_bf16(a, b1, acc1, 0, 0, 0);
  }
  #pragma unroll
  for (int v=0; v<4; v++){
    acc0[v] += __shfl_down(acc0[v], 32);
    acc1[v] += __shfl_down(acc1[v], 32);
  }
  if (kgrp < 2){
    int rb = kgrp*4;
    int c0 = n0*16 + mrow, c1 = c0 + 16;
    #pragma unroll
    for (int v=0; v<4; v++){
      gates[(rb+v)*NC + c0] = acc0[v] + bv0;
      gates[(rb+v)*NC + c1] = acc1[v] + bv1;
    }
  }
}

// Fused activation + PAIR EXCHANGE. 512 threads = 8 rows x 64 own-units.
// own h: -> xh tiles + f32 agent-atomic store to own mailbox (XCD-coherent);
// per-wave vmcnt(0) drain -> lane0 atomicAdd(flag) RELEASE (8/step);
// lane0 spins ACQUIRE on partner flag >= 8*(step+1); partner h loaded with
// agent-atomic f32 loads (never stale) -> xh tiles. One bar_lds at the end
// (same 2-barriers-per-layer-step as R2). Protocol safety: partner flag at
// s+2 implies it finished READING slot s, so mailbox reuse (3-slot, =layer)
// never overtakes a reader. Both WGs send before spinning -> no circular wait.
template<bool NEXT, bool H2>
__device__ __forceinline__ void act_ex(const float* __restrict__ gates, float& cref,
                                       u16* __restrict__ xh_self, int din_self,
                                       u16* __restrict__ xh_next,
                                       float* __restrict__ h2S,
                                       float* __restrict__ mb_out,
                                       const float* __restrict__ mb_in,
                                       uint32* __restrict__ fl_self,
                                       uint32* __restrict__ fl_part,
                                       int step, int role, int tid, int lane)
{
  const int r = tid >> 6, u = tid & 63;     // wave = row r
  const int l3 = (step % 3) << 9;           // 512-f32 slot per layer
  const float* g = gates + r*NC;
  float ig = sigm (g[u]);
  float fg = sigm (g[u + 64]);
  float gg = tanh_(g[u + 128]);
  float og = sigm (g[u + 192]);
  cref = fg*cref + ig*gg;
  float hv = og*tanh_(cref);
  const int unit = role*64 + u;
  wr_xh(xh_self, r, din_self + unit, hv);
  if (NEXT) wr_xh(xh_next, r, unit, hv);
  if (H2)   h2S[r*Hn + unit] = hv;
  __hip_atomic_store(&mb_out[l3 + r*64 + u], hv,
                     __ATOMIC_RELAXED, __HIP_MEMORY_SCOPE_AGENT);
  asm volatile("s_waitcnt vmcnt(0)" ::: "memory");       // this wave's stores done
  if (lane == 0)
    __hip_atomic_fetch_add(fl_self, 1u, __ATOMIC_RELEASE, __HIP_MEMORY_SCOPE_AGENT);
  const uint32 want = 8u*(uint32)(step + 1);
  if (lane == 0){
    while (__hip_atomic_load(fl_part, __ATOMIC_ACQUIRE, __HIP_MEMORY_SCOPE_AGENT) < want)
      __builtin_amdgcn_s_sleep(1);
  }
  float hp = __hip_atomic_load(&mb_in[l3 + r*64 + u],
                               __ATOMIC_RELAXED, __HIP_MEMORY_SCOPE_AGENT);
  const int unitp = (1 - role)*64 + u;
  wr_xh(xh_self, r, din_self + unitp, hp);
  if (NEXT) wr_xh(xh_next, r, unitp, hp);
  if (H2)   h2S[r*Hn + unitp] = hp;
  bar_lds();
}

// OUTPUT IS FP32. Both roles compute the FULL projection (identical values ->
// duplicate stores are benign); avoids a pred exchange. fwtS[k*52+d] reads are
// consecutive floats per k = conflict-free. pred feeds xh0.x directly.
__device__ __forceinline__ void proj_out(const float* __restrict__ h2S,
                                         const float* __restrict__ fwtS,
                                         const float* __restrict__ fbwS,
                                         u16* __restrict__ xh0,
                                         float* __restrict__ out, long b0, int t, int tid)
{
  int r = tid >> 6, d = tid & 63;
  float acc = 0.f;
  if (d < 52){
    const float* h = h2S + r*Hn;
    #pragma unroll 8
    for (int k=0;k<Hn;k++) acc += h[k] * fwtS[k*52 + d];
  }
  if (d < Dn){
    float pv = acc + fbwS[d];
    out[((size_t)(b0+r)*Tn + (Tn-1-t))*Dn + d] = pv;
    wr_xh(xh0, r, d, pv);
  }
}

// 512 threads, min 4 waves/EU -> VGPR cap 128 (expect ~60). LDS ~63 KB ->
// 2 WGs/CU: all 512 WGs co-resident by construction (required by the spin).
__global__ __launch_bounds__(NTH, 4) void lstm_kernel(
    const float* __restrict__ src, const u16* __restrict__ wsw,
    const float* __restrict__ bias, const float* __restrict__ fwt,
    const float* __restrict__ fbw, float* __restrict__ out,
    float* __restrict__ mbox, uint32* __restrict__ flags)
{
  __shared__ __align__(16) u16   xhA[3*16*RP];    // 24.75 KB (full-K A-tiles)
  __shared__ __align__(16) float gates[BR*NC];    // 8 KB (own half)
  __shared__ __align__(16) float fwtS[FWTE];      // 26 KB f32
  __shared__ __align__(16) float h2S[BR*Hn];      // 4 KB (full h2, post-exchange)
  __shared__ __align__(16) float fbwS[64];        // 0.25 KB   (~63 KB total)

  const int tid = threadIdx.x;
  const int wave = tid >> 6, lane = tid & 63;
  const int wg = blockIdx.x, role = wg >> 8;
  const long b0 = (long)(wg & 255) * BR;
  const int pwg = wg ^ 256;                       // partner (same CU slot +256)
  float*        mb_out = mbox + (size_t)wg  * 1536;   // 3 slots x 512 f32
  const float*  mb_in  = mbox + (size_t)pwg * 1536;
  uint32* fl_self = flags + wg;
  uint32* fl_part = flags + pwg;

  u16* xh0 = xhA;
  u16* xh1 = xhA + 16*RP;
  u16* xh2 = xhA + 32*RP;

  const u16* wsE0 = wsw + (0*2 + role)*65536;
  const u16* wsE1 = wsw + (1*2 + role)*65536;
  const u16* wsE2 = wsw + (2*2 + role)*65536;
  const u16* wsD0 = wsw + (3*2 + role)*65536;
  const u16* wsD1 = wsw + (4*2 + role)*65536;
  const u16* wsD2 = wsw + (5*2 + role)*65536;

  // persistent per-thread c-state (thread -> (row tid>>6, own unit tid&63))
  float c0 = 0.f, c1 = 0.f, c2 = 0.f;
  // epilogue biases (own-col space), 12 regs
  const int cb = wave*32 + (lane & 15);
  #define LB(l,o) bias[(l)*512 + role*256 + cb + (o)]
  float bE0a=LB(0,0), bE0b=LB(0,16), bE1a=LB(1,0), bE1b=LB(1,16);
  float bE2a=LB(2,0), bE2b=LB(2,16), bD0a=LB(3,0), bD0b=LB(3,16);
  float bD1a=LB(4,0), bD1b=LB(4,16), bD2a=LB(5,0), bD2b=LB(5,16);
  #undef LB

  // src(0) prefetch: 8 rows x 51, one value per thread
  float sV = 0.f;
  { int r = tid >> 6, k = tid & 63;
    if (k < Dn) sV = src[((size_t)(b0+r)*Tn + 0)*Dn + k]; }

  // ---- init LDS ----
  for (int i=tid; i<FWTE; i+=NTH) fwtS[i] = fwt[i];
  if (tid < 64) fbwS[tid] = fbw[tid];
  for (int i=tid; i<3*16*RP; i+=NTH) xhA[i] = 0;   // pads stay 0 forever
  __syncthreads();
  { int r = tid >> 6, k = tid & 63;
    if (k < Dn) wr_xh(xh0, r, k, sV); }            // src(0) -> xh0.x
  __syncthreads();

  // ---------------- encoder ----------------
  for (int t=0;t<Tn;t++){
    int tn = (t < Tn-1) ? t+1 : Tn-1;
    { int r = tid >> 6, k = tid & 63;              // src(t+1) -> reg
      if (k < Dn) sV = src[((size_t)(b0+r)*Tn + tn)*Dn + k]; }
    gemm_mfma<6>(wsE0, bE0a, bE0b, xh0, gates, wave, lane);
    bar_lds();
    if (t < Tn-1){ int r = tid >> 6, k = tid & 63; // xh0.x idle until next l0
      if (k < Dn) wr_xh(xh0, r, k, sV); }
    act_ex<true ,false>(gates, c0, xh0, Dn, xh1, h2S, mb_out, mb_in,
                        fl_self, fl_part, t*3 + 0, role, tid, lane);

    gemm_mfma<8>(wsE1, bE1a, bE1b, xh1, gates, wave, lane);
    bar_lds();
    act_ex<true ,false>(gates, c1, xh1, Hn, xh2, h2S, mb_out, mb_in,
                        fl_self, fl_part, t*3 + 1, role, tid, lane);

    gemm_mfma<8>(wsE2, bE2a, bE2b, xh2, gates, wave, lane);
    bar_lds();
    act_ex<false,false>(gates, c2, xh2, Hn, (u16*)nullptr, h2S, mb_out, mb_in,
                        fl_self, fl_part, t*3 + 2, role, tid, lane);
  }

  // ---------------- decoder ----------------
  // xh*.h-parts + c regs carry enc-final state. Reset xh0.x to pred(-1)=0.
  { int r = tid >> 6, k = tid & 63;
    if (k < Dn){ xh0[r*RP + k] = 0; xh0[(r+8)*RP + k] = 0; } }
  bar_lds();

  for (int t=0;t<Tn;t++){
    int sb = 300 + t*3;
    gemm_mfma<6>(wsD0, bD0a, bD0b, xh0, gates, wave, lane);
    bar_lds();
    act_ex<true ,false>(gates, c0, xh0, Dn, xh1, h2S, mb_out, mb_in,
                        fl_self, fl_part, sb + 0, role, tid, lane);

    gemm_mfma<8>(wsD1, bD1a, bD1b, xh1, gates, wave, lane);
    bar_lds();
    act_ex<true ,false>(gates, c1, xh1, Hn, xh2, h2S, mb_out, mb_in,
                        fl_self, fl_part, sb + 1, role, tid, lane);

    gemm_mfma<8>(wsD2, bD2a, bD2b, xh2, gates, wave, lane);
    bar_lds();
    act_ex<false,true >(gates, c2, xh2, Hn, (u16*)nullptr, h2S, mb_out, mb_in,
                        fl_self, fl_part, sb + 2, role, tid, lane);

    proj_out(h2S, fwtS, fbwS, xh0, out, b0, t, tid);
    bar_lds();
  }
}

extern "C" void kernel_launch(void* const* d_in, const int* in_sizes, int n_in,
                              void* d_out, int out_size, void* d_ws, size_t ws_size,
                              hipStream_t stream)
{
  (void)in_sizes; (void)n_in; (void)out_size; (void)ws_size;
  const float* src = (const float*)d_in[0];
  WP p;
  for (int l=0;l<3;l++){
    p.W[l]    = (const float*)d_in[1  + 3*l];
    p.U[l]    = (const float*)d_in[2  + 3*l];
    p.Bb[l]   = (const float*)d_in[3  + 3*l];
    p.W[3+l]  = (const float*)d_in[10 + 3*l];
    p.U[3+l]  = (const float*)d_in[11 + 3*l];
    p.Bb[3+l] = (const float*)d_in[12 + 3*l];
  }
  p.fW = (const float*)d_in[19];
  p.fb = (const float*)d_in[20];

  // ws: wsw u16[786432] | bias f32[3072] | fwt f32[6656] | fbw f32[64]
  //   | flags u32[512] | mbox f32[512*1536]  (~4.7 MB total)
  u16*    wsw   = (u16*)d_ws;
  float*  bias  = (float*)((char*)d_ws + 6*131072*sizeof(u16));
  float*  fwt   = bias + 6*512;
  float*  fbw   = fwt + FWTE;
  uint32* flags = (uint32*)(fbw + 64);
  float*  mbox  = (float*)(flags + NWG);

  prep_kernel<<<(PREP_TOTAL + 255)/256, 256, 0, stream>>>(p, wsw, bias, fwt, fbw, flags);
  lstm_kernel<<<NWG, NTH, 0, stream>>>(src, wsw, bias, fwt, fbw, (float*)d_out,
                                       mbox, flags);
}

// Round 11
// 3524.154 us; speedup vs baseline: 17.5622x; 17.5622x over previous
//
#include <hip/hip_runtime.h>
#include <stdint.h>

#define Tn 100
#define Dn 51
#define Hn 128
#define G4 512     // 4*H
#define BR 8       // batch rows per workgroup
#define NWG 256    // workgroups (2048 / 8) = 1 WG/CU
#define NTH 1024   // 16 waves, 4/SIMD
#define RP 264     // xhA row stride in bf16 elems (16B-aligned rows)

typedef unsigned int uint32;
typedef unsigned short u16;
typedef short s16x8 __attribute__((ext_vector_type(8)));   // 8 bf16 = 4 VGPRs
typedef float f32x4v __attribute__((ext_vector_type(4)));

__device__ __forceinline__ float rcp_(float x){ return __builtin_amdgcn_rcpf(x); }
__device__ __forceinline__ float sigm(float x){ return rcp_(1.f + __expf(-x)); }
__device__ __forceinline__ float tanh_(float x){ return 1.f - 2.f*rcp_(1.f + __expf(2.f*x)); }

// fp32 -> bf16 round-to-nearest-even
__device__ __forceinline__ u16 f2bf(float f){
  uint32 u = __float_as_uint(f);
  return (u16)((u + 0x7fffu + ((u >> 16) & 1u)) >> 16);
}
__device__ __forceinline__ float bf2f(u16 u){ return __uint_as_float(((uint32)u)<<16); }

// A-fragment trick: row r (0..7) = bf16-hi of xh row r; row r+8 = bf16-lo.
// One MFMA computes both pumps; epilogue sums D[r] + D[r+8] via shfl.
__device__ __forceinline__ void wr_xh(u16* __restrict__ xhA, int r, int k, float v){
  u16 h = f2bf(v);
  xhA[r*RP + k]     = h;
  xhA[(r+8)*RP + k] = f2bf(v - bf2f(h));
}

struct WP {
  const float* W[6];   // [4H, din]  enc0..2, dec0..2 (fp32)
  const float* U[6];   // [4H, H]
  const float* Bb[6];  // [4H]
  const float* fW;     // [D, H]
  const float* fb;     // [D]
};

// ws: wsw = MFMA-B-fragment-swizzled bf16 weights.
// Layout per layer (uniform 131072 u16): chunk (n,s) at ((n*8+s)*64+lane)*8+j,
// holding Wc[k = s*32+(lane>>4)*8+j][c = n*16+(lane&15)], Wc = [Wih | Whh] along k,
// zero-padded (k>=K or s>=S). A wave's B-frag load = contiguous 1KB dwordx4.
// fwt: [128][64] f32 (k-major, d minor, d>=51 pad 0) -- proj reads 64 consecutive
// floats per k across 64 lanes = conflict-free.
#define PREP_TOTAL (6*131072 + 6*512 + 8192 + 64)
__global__ void prep_kernel(WP p, u16* __restrict__ wsw, float* __restrict__ bias,
                            float* __restrict__ fwt, float* __restrict__ fbw)
{
  int gid = blockIdx.x*256 + threadIdx.x;
  if (gid >= PREP_TOTAL) return;
  if (gid < 6*131072){
    int l = gid >> 17;
    int e = gid & 131071;
    int n    = e >> 12;
    int s    = (e >> 9) & 7;
    int lane = (e >> 3) & 63;
    int j    = e & 7;
    int k = s*32 + (lane >> 4)*8 + j;
    int c = n*16 + (lane & 15);
    int din = (l % 3 == 0) ? Dn : Hn;
    int K = din + Hn;
    u16 v = 0;
    if (k < K){
      float f = (k < din) ? p.W[l][(size_t)c*din + k] : p.U[l][(size_t)c*Hn + (k - din)];
      v = f2bf(f);
    }
    wsw[gid] = v;
  } else if (gid < 6*131072 + 6*512){
    int i = gid - 6*131072;
    bias[i] = p.Bb[i>>9][i & 511];
  } else if (gid < 6*131072 + 6*512 + 8192){
    int i = gid - (6*131072 + 6*512);
    int k = i >> 6, d = i & 63;
    fwt[i] = (d < Dn) ? p.fW[(size_t)d*Hn + k] : 0.f;
  } else {
    int d = gid - (6*131072 + 6*512 + 8192);
    fbw[d] = (d < Dn) ? p.fb[d] : 0.f;
  }
}

// LDS-only barrier: drains DS ops, NOT vmcnt (src prefetch stays in flight).
// All cross-thread data in this kernel lives in LDS; 'out' is never read back.
__device__ __forceinline__ void bar_lds(){
  asm volatile("s_waitcnt lgkmcnt(0)" ::: "memory");
  __builtin_amdgcn_s_barrier();
}

// gates[r][c] = bias[c] + sum_k xh[r][k]*Wc[k][c] via mfma_f32_16x16x32_bf16.
// Wave w owns N-tiles n0=2w, 2w+1.
// R11 RETEST of R7: identical gemm (ALL S*2 B-frags staged to registers up
// front -- pays the L2 latency once per gemm), but __launch_bounds__(NTH, 2).
// R7 at bounds(.,4) hit the allocator cliff: it pinned VGPR=64 and spilled
// 7.4 GB instead of allocating the ~110 the staging needs (cap was 128).
// bounds(.,2) raises the compiler budget to 256; if it allocates 100-128 the
// RUNTIME occupancy is unchanged (m69 tier: <=128 -> 4 waves/SIMD) and the
// staging window finally runs. Tripwires pre-committed: VGPR>128 = occupancy
// halved (expect ~2300+); VGPR=64 + FETCH in GBs = cliff is bounds-independent.
// Either failure -> revert to R2 (1850us) and settle.
// C/D: col=lane&15, row=(lane>>4)*4+reg (m89) -> rows in lanes 0-31, +8 in 32-63.
template<int S>
__device__ __forceinline__ void gemm_stage(const u16* __restrict__ wsl,
                                           float bv0, float bv1,
                                           const u16* __restrict__ xh_in,
                                           float* __restrict__ gates,
                                           int wave, int lane)
{
  const int mrow = lane & 15, kgrp = lane >> 4;
  const int n0 = wave*2;
  const u16* bp0 = wsl + n0*4096 + lane*8;
  const int aoff = mrow*RP + (kgrp << 3);
  s16x8 B0[S], B1[S];
  #pragma unroll
  for (int s=0; s<S; s++){
    B0[s] = *(const s16x8*)(bp0 + s*512);
    B1[s] = *(const s16x8*)(bp0 + 4096 + s*512);
  }
  __builtin_amdgcn_sched_barrier(0);   // keep the 2S loads clustered ahead of MFMAs
  f32x4v acc0 = {0.f,0.f,0.f,0.f}, acc1 = {0.f,0.f,0.f,0.f};
  #pragma unroll
  for (int s=0; s<S; s++){
    s16x8 a = *(const s16x8*)(xh_in + aoff + s*32);
    acc0 = __builtin_amdgcn_mfma_f32_16x16x32_bf16(a, B0[s], acc0, 0, 0, 0);
    acc1 = __builtin_amdgcn_mfma_f32_16x16x32_bf16(a, B1[s], acc1, 0, 0, 0);
  }
  // fold lo-product rows (A rows 8-15, lanes 32-63) into hi rows (lanes 0-31)
  #pragma unroll
  for (int v=0; v<4; v++){
    float l0 = __shfl_down(acc0[v], 32);
    float l1 = __shfl_down(acc1[v], 32);
    acc0[v] += l0;
    acc1[v] += l1;
  }
  if (kgrp < 2){
    int rb = kgrp*4;
    int c0g = n0*16 + mrow, c1g = c0g + 16;
    #pragma unroll
    for (int v=0; v<4; v++){
      gates[(rb+v)*G4 + c0g] = acc0[v] + bv0;
      gates[(rb+v)*G4 + c1g] = acc1[v] + bv1;
    }
  }
}

// Fused activation: gates -> (h, c-in-REGISTER), h written straight into the
// A-tiles that consume it. Thread->(r,j) map is static across the kernel, so
// c-state is one VGPR per layer per thread (no cS LDS traffic).
__device__ __forceinline__ void activate2(const float* __restrict__ gates, float& cref,
                                          u16* __restrict__ xh_self, int din_self,
                                          u16* __restrict__ xh_next,
                                          float* __restrict__ h2S, int tid)
{
  int r = tid >> 7, j = tid & 127;       // 1024 threads = 8 rows x 128
  const float* g = gates + r*G4;
  float ig = sigm (g[j]);
  float fg = sigm (g[j + Hn]);
  float gg = tanh_(g[j + 2*Hn]);
  float og = sigm (g[j + 3*Hn]);
  cref = fg*cref + ig*gg;
  float hv = og*tanh_(cref);
  wr_xh(xh_self, r, din_self + j, hv);
  if (xh_next) wr_xh(xh_next, r, j, hv);
  if (h2S)     h2S[r*Hn + j] = hv;
}

// OUTPUT IS FP32. 8 rows x 64 cols = 512 work items; fwtS[k*64+d] reads are
// 64-consecutive-float per k = conflict-free. pred feeds xh0.x directly.
__device__ __forceinline__ void proj_out(const float* __restrict__ h2S,
                                         const float* __restrict__ fwtS,
                                         const float* __restrict__ fbwS,
                                         u16* __restrict__ xh0,
                                         float* __restrict__ out, long b0, int t, int tid)
{
  if (tid < 512){
    int r = tid >> 6, d = tid & 63;
    const float* h = h2S + r*Hn;
    float acc = 0.f;
    #pragma unroll 8
    for (int k=0;k<Hn;k++) acc += h[k] * fwtS[k*64 + d];
    if (d < Dn){
      float pv = acc + fbwS[d];
      out[((size_t)(b0+r)*Tn + (Tn-1-t))*Dn + d] = pv;
      wr_xh(xh0, r, d, pv);
    }
  }
}

// (1024, 2): compiler VGPR budget 256 (the one-variable change vs R7).
// Runtime occupancy is set by the ACTUAL allocation: <=128 keeps 4 waves/SIMD.
__global__ __launch_bounds__(NTH, 2) void lstm_kernel(
    const float* __restrict__ src, const u16* __restrict__ wsw,
    const float* __restrict__ bias, const float* __restrict__ fwt,
    const float* __restrict__ fbw, float* __restrict__ out)
{
  __shared__ __align__(16) u16   xhA[3*16*RP];    // 24.75 KB per-layer A-tiles
  __shared__ __align__(16) float gates[BR*G4];    // 16 KB
  __shared__ __align__(16) float fwtS[8192];      // 32 KB f32 (accuracy: keep f32)
  __shared__ __align__(16) float h2S[BR*Hn];      // 4 KB dec-l2 h for proj
  __shared__ __align__(16) float fbwS[64];        // 0.25 KB   (total ~77 KB)

  const int tid = threadIdx.x;
  const int wave = tid >> 6, lane = tid & 63;
  const long b0 = (long)blockIdx.x * BR;
  u16* xh0 = xhA;
  u16* xh1 = xhA + 16*RP;
  u16* xh2 = xhA + 32*RP;

  const u16* wsE0 = wsw;
  const u16* wsE1 = wsw + 1*131072;
  const u16* wsE2 = wsw + 2*131072;
  const u16* wsD0 = wsw + 3*131072;
  const u16* wsD1 = wsw + 4*131072;
  const u16* wsD2 = wsw + 5*131072;

  // persistent per-thread state: c for 3 layers (act mapping r=tid>>7,j=tid&127)
  float c0 = 0.f, c1 = 0.f, c2 = 0.f;
  // per-thread epilogue biases for columns c0g, c0g+16, all 6 layers (12 VGPRs)
  const int c0g = wave*32 + (lane & 15);
  #define LB(l,o) bias[(l)*G4 + c0g + (o)]
  float bE0a=LB(0,0), bE0b=LB(0,16), bE1a=LB(1,0), bE1b=LB(1,16);
  float bE2a=LB(2,0), bE2b=LB(2,16), bD0a=LB(3,0), bD0b=LB(3,16);
  float bD1a=LB(4,0), bD1b=LB(4,16), bD2a=LB(5,0), bD2b=LB(5,16);
  #undef LB

  // src(0) prefetch
  float sA = 0.f, sB = 0.f;
  { int kk = tid & 255;
    if (kk < Dn){ int r0 = tid >> 8;
      sA = src[((size_t)(b0+r0)*Tn + 0)*Dn + kk];
      sB = src[((size_t)(b0+r0+4)*Tn + 0)*Dn + kk]; } }

  // ---- init LDS ----
  for (int i=tid; i<8192; i+=NTH) fwtS[i] = fwt[i];
  if (tid < 64) fbwS[tid] = fbw[tid];
  for (int i=tid; i<3*16*RP; i+=NTH) xhA[i] = 0;   // pads stay 0 forever
  __syncthreads();
  { int kk = tid & 255;
    if (kk < Dn){ int r0 = tid >> 8;
      wr_xh(xh0, r0,   kk, sA);
      wr_xh(xh0, r0+4, kk, sB); } }                // src(0) -> xh0.x
  __syncthreads();

  // ---------------- encoder: 6 lgkm-barriers per t ----------------
  for (int t=0;t<Tn;t++){
    int tn = (t < Tn-1) ? t+1 : Tn-1;
    { int kk = tid & 255;                          // src(t+1) -> regs
      if (kk < Dn){ int r0 = tid >> 8;
        sA = src[((size_t)(b0+r0)*Tn + tn)*Dn + kk];
        sB = src[((size_t)(b0+r0+4)*Tn + tn)*Dn + kk]; } }
    gemm_stage<6>(wsE0, bE0a, bE0b, xh0, gates, wave, lane);
    bar_lds();
    activate2(gates, c0, xh0, Dn, xh1, nullptr, tid);
    if (t < Tn-1){ int kk = tid & 255;             // xh0.x idle during act-l0
      if (kk < Dn){ int r0 = tid >> 8;
        wr_xh(xh0, r0,   kk, sA);
        wr_xh(xh0, r0+4, kk, sB); } }
    bar_lds();

    gemm_stage<8>(wsE1, bE1a, bE1b, xh1, gates, wave, lane);
    bar_lds();
    activate2(gates, c1, xh1, Hn, xh2, nullptr, tid);
    bar_lds();

    gemm_stage<8>(wsE2, bE2a, bE2b, xh2, gates, wave, lane);
    bar_lds();
    activate2(gates, c2, xh2, Hn, nullptr, nullptr, tid);
    bar_lds();
  }

  // ---------------- decoder ----------------
  // xh*.h-parts + c regs carry enc-final state. Reset xh0.x to pred(-1)=0.
  { int r = tid >> 7, kk = tid & 127;
    if (kk < Dn){ xh0[r*RP + kk] = 0; xh0[(r+8)*RP + kk] = 0; } }
  bar_lds();

  for (int t=0;t<Tn;t++){
    gemm_stage<6>(wsD0, bD0a, bD0b, xh0, gates, wave, lane);
    bar_lds();
    activate2(gates, c0, xh0, Dn, xh1, nullptr, tid);
    bar_lds();

    gemm_stage<8>(wsD1, bD1a, bD1b, xh1, gates, wave, lane);
    bar_lds();
    activate2(gates, c1, xh1, Hn, xh2, nullptr, tid);
    bar_lds();

    gemm_stage<8>(wsD2, bD2a, bD2b, xh2, gates, wave, lane);
    bar_lds();
    activate2(gates, c2, xh2, Hn, nullptr, h2S, tid);
    bar_lds();

    proj_out(h2S, fwtS, fbwS, xh0, out, b0, t, tid);
    bar_lds();
  }
}

extern "C" void kernel_launch(void* const* d_in, const int* in_sizes, int n_in,
                              void* d_out, int out_size, void* d_ws, size_t ws_size,
                              hipStream_t stream)
{
  (void)in_sizes; (void)n_in; (void)out_size; (void)ws_size;
  const float* src = (const float*)d_in[0];
  WP p;
  for (int l=0;l<3;l++){
    p.W[l]    = (const float*)d_in[1  + 3*l];
    p.U[l]    = (const float*)d_in[2  + 3*l];
    p.Bb[l]   = (const float*)d_in[3  + 3*l];
    p.W[3+l]  = (const float*)d_in[10 + 3*l];
    p.U[3+l]  = (const float*)d_in[11 + 3*l];
    p.Bb[3+l] = (const float*)d_in[12 + 3*l];
  }
  p.fW = (const float*)d_in[19];
  p.fb = (const float*)d_in[20];

  // ws: wsw u16[786432] (1.5MB) | bias f32[3072] | fwt f32[8192] | fbw f32[64]
  u16*   wsw  = (u16*)d_ws;
  float* bias = (float*)((char*)d_ws + 6*131072*sizeof(u16));
  float* fwt  = bias + 6*512;
  float* fbw  = fwt + 8192;

  prep_kernel<<<(PREP_TOTAL + 255)/256, 256, 0, stream>>>(p, wsw, bias, fwt, fbw);
  lstm_kernel<<<NWG, NTH, 0, stream>>>(src, wsw, bias, fwt, fbw, (float*)d_out);
}